// Round 15
// baseline (291.683 us; speedup 1.0000x reference)
//
#include <hip/hip_runtime.h>
#include <hip/hip_bf16.h>
#include <math.h>

#define HH    48
#define CFEAT 512
#define HID   256
#define NPOS  (HH*HH)   // 2304
#define TQ    48        // queries per block
#define NEV   192       // evals per block = TQ*4
#define NB    1366      // blocks per batch = ceil(65536/48)

typedef __attribute__((ext_vector_type(8))) short bf16x8;
typedef __attribute__((ext_vector_type(4))) float f32x4;

static __device__ __forceinline__ unsigned short f2bf(float x) {
  unsigned int u = __float_as_uint(x);
  u += 0x7fffu + ((u >> 16) & 1u);     // RNE
  return (unsigned short)(u >> 16);
}

// packed f32x2 -> bf16x2 via v_cvt_pk_bf16_f32 (RNE)
static __device__ __forceinline__ unsigned int pk2bf(float a, float b) {
  __hip_bfloat162 h2 = __float22bfloat162_rn(make_float2(a, b));
  unsigned int u; __builtin_memcpy(&u, &h2, 4); return u;
}

// index/rel math shared (bit-exact) by Phase A and blend-area recompute
static __device__ __forceinline__ void rel_calc(float c0, float c1, int s,
                                                float& r0, float& r1,
                                                int& ir, int& ic) {
  float vx = (s & 2) ? 1.0f : -1.0f;
  float vy = (s & 1) ? 1.0f : -1.0f;
  const float RXY = (float)(1.0/48.0);
  const float CLO = (float)(-1.0 + 1e-6);
  const float CHI = (float)( 1.0 - 1e-6);
  float gx = __fadd_rn(c0, __fadd_rn(__fmul_rn(vx, RXY), 1e-6f));
  float gy = __fadd_rn(c1, __fadd_rn(__fmul_rn(vy, RXY), 1e-6f));
  gx = fminf(fmaxf(gx, CLO), CHI);
  gy = fminf(fmaxf(gy, CLO), CHI);
  float xr = __fmul_rn(__fsub_rn(__fmul_rn(__fadd_rn(gx, 1.0f), 48.0f), 1.0f), 0.5f);
  float xc = __fmul_rn(__fsub_rn(__fmul_rn(__fadd_rn(gy, 1.0f), 48.0f), 1.0f), 0.5f);
  ir = (int)rintf(xr); ir = ir < 0 ? 0 : (ir > HH-1 ? HH-1 : ir);
  ic = (int)rintf(xc); ic = ic < 0 ? 0 : (ic > HH-1 ? HH-1 : ic);
  const float T2 = (float)(2.0/48.0);
  float qcr = __fsub_rn(__fmul_rn(__fadd_rn((float)ir, 0.5f), T2), 1.0f);
  float qcc = __fsub_rn(__fmul_rn(__fadd_rn((float)ic, 0.5f), T2), 1.0f);
  r0 = __fmul_rn(__fsub_rn(c0, qcr), 48.0f);
  r1 = __fmul_rn(__fsub_rn(c1, qcc), 48.0f);
}

// ---------------------------------------------------------------------------
// Kernel 1: P[b][pos][n] = b0[n] + sum_c feat[b][c][pos] * W0[c][n]  (fp32)
// ---------------------------------------------------------------------------
__global__ __launch_bounds__(256) void liif_precompute(
    const float* __restrict__ feat, const float* __restrict__ W0,
    const float* __restrict__ b0, float* __restrict__ P)
{
  int blk = blockIdx.x;                 // 0..1151
  int b   = blk / (NPOS/4);
  int p0  = (blk - b*(NPOS/4)) * 4;
  int n   = threadIdx.x;
  const float* f = feat + (size_t)b * CFEAT * NPOS + p0;
  float bias = b0[n];
  float a0 = bias, a1 = bias, a2 = bias, a3 = bias;
  #pragma unroll 4
  for (int c = 0; c < CFEAT; ++c) {
    float w = W0[c*HID + n];
    const float* fr = f + (size_t)c * NPOS;
    a0 += fr[0]*w; a1 += fr[1]*w; a2 += fr[2]*w; a3 += fr[3]*w;
  }
  float* Pp = P + ((size_t)b*NPOS + p0)*HID + n;
  Pp[0*HID] = a0; Pp[1*HID] = a1; Pp[2*HID] = a2; Pp[3*HID] = a3;
}

// ---------------------------------------------------------------------------
// Kernel 2: build pre-permuted W image for linear global_load_lds staging.
// Chunk (l,kc) = 16 KB; 16-B unit p (0..1023):
//   wc = p>>8, nt = (p>>6)&3, lane = p&63, lr = lane&15, lk = lane>>4
//   n = wc*64 + nt*16 + lr ; unit holds Wt[n][kc*32 + lk*8 .. +8]
// Read addr (wc, lane, nt) = wc*4096 + nt*1024 + lane*16 -> conflict-free.
// Layer stride = 8 chunks = 131072 B. Also W4 -> f32 W4t[o][k].
// ---------------------------------------------------------------------------
__global__ __launch_bounds__(256) void liif_convert(
    const float* __restrict__ W1, const float* __restrict__ W2,
    const float* __restrict__ W3, const float* __restrict__ W4,
    unsigned char* __restrict__ img, float* __restrict__ w4t)
{
  int blk = blockIdx.x, t = threadIdx.x;
  if (blk < 24) {
    int l = blk >> 3, kc = blk & 7;
    const float* W = (l == 0) ? W1 : (l == 1) ? W2 : W3;
    unsigned short* dst = (unsigned short*)(img + (size_t)blk * 16384);
    #pragma unroll 1
    for (int s = 0; s < 4; ++s) {
      int p    = t + s*256;
      int wc   = p >> 8;
      int nt   = (p >> 6) & 3;
      int lane = p & 63;
      int lr   = lane & 15, lk = lane >> 4;
      int n    = wc*64 + nt*16 + lr;
      int k0   = kc*32 + lk*8;
      #pragma unroll
      for (int j = 0; j < 8; ++j)
        dst[p*8 + j] = f2bf(W[(k0 + j)*256 + n]);
    }
  } else {
    for (int o = 0; o < 3; ++o) w4t[o*256 + t] = W4[t*3 + o];
  }
}

// ---------------------------------------------------------------------------
// Kernel 3: fused main. 192 evals/block, 768 thr / 12 waves (3x4 of 64x64).
// act: XOR-swizzled [192 rows][512 B] = 96 KB.
// W: 32 KB groups (2 K-chunks) double-buffered (2x32 KB) via global_load_lds;
// per group: issue next DMA, 2 barrier-free ksteps, 1 barrier. All DMA
// overlapped with compute. LDS = exactly 160 KiB.
// ---------------------------------------------------------------------------
// LDS map:
//   [0, 98304)        act (swizzled). After L3: predp overlay (9.2 KB).
//   [98304, 131072)   wbuf0 (32 KB); first 4 KB = {lin_s, rel4} in Phase A/B.
//   [131072, 163840)  wbuf1 (32 KB).

#define WBASE  98304

#define MF(A, B, C) __builtin_amdgcn_mfma_f32_16x16x32_bf16((A), (B), (C), 0, 0, 0)

#define AS1(p) ((const __attribute__((address_space(1))) void*)(unsigned long long)(const void*)(p))
#define AS3(p) ((__attribute__((address_space(3))) void*)(unsigned int)(unsigned long long)(void*)(p))

// DMA one 32 KB group (32 x 1KB slices) with 12 waves:
// ops j=0,1 all waves (slices j*12+w), op j=2 waves 0..7 (slices 24..31).
#define STAGEG(GOFF, BUF) do {                                                \
    __builtin_amdgcn_global_load_lds(                                         \
        AS1(img + (GOFF) + sgoff),                                            \
        AS3(lds + WBASE + (BUF)*32768 + swoff), 16, 0, 0);                    \
    __builtin_amdgcn_global_load_lds(                                         \
        AS1(img + (GOFF) + 12288 + sgoff),                                    \
        AS3(lds + WBASE + (BUF)*32768 + 12288 + swoff), 16, 0, 0);            \
    if (w < 8)                                                                \
      __builtin_amdgcn_global_load_lds(                                       \
          AS1(img + (GOFF) + 24576 + sgoff),                                  \
          AS3(lds + WBASE + (BUF)*32768 + 24576 + swoff), 16, 0, 0);          \
  } while (0)

// one K=32 step: 4 W + 4 act b128 reads, 16 MFMA. NO barrier.
// W chunk KC lives at wbuf[(KC>>1)&1] + (KC&1)*16384.
#define KSTEPC(KC) do {                                                       \
    const unsigned char* wb_ = lds + WBASE + (((KC) >> 1) & 1)*32768          \
                             + (((KC) & 1)*16384) + lwoff;                    \
    bf16x8 w0_ = *(const bf16x8*)(wb_ + 0);                                   \
    bf16x8 w1_ = *(const bf16x8*)(wb_ + 1024);                                \
    bf16x8 w2_ = *(const bf16x8*)(wb_ + 2048);                                \
    bf16x8 w3_ = *(const bf16x8*)(wb_ + 3072);                                \
    const int ko_ = (((KC) << 6) ^ xb6);                                      \
    bf16x8 a0_ = *(const bf16x8*)(lds + rb0 + ko_);                           \
    bf16x8 a1_ = *(const bf16x8*)(lds + rb1 + ko_);                           \
    bf16x8 a2_ = *(const bf16x8*)(lds + rb2 + ko_);                           \
    bf16x8 a3_ = *(const bf16x8*)(lds + rb3 + ko_);                           \
    acc[0]  = MF(w0_, a0_, acc[0]);  acc[1]  = MF(w1_, a0_, acc[1]);          \
    acc[2]  = MF(w2_, a0_, acc[2]);  acc[3]  = MF(w3_, a0_, acc[3]);          \
    acc[4]  = MF(w0_, a1_, acc[4]);  acc[5]  = MF(w1_, a1_, acc[5]);          \
    acc[6]  = MF(w2_, a1_, acc[6]);  acc[7]  = MF(w3_, a1_, acc[7]);          \
    acc[8]  = MF(w0_, a2_, acc[8]);  acc[9]  = MF(w1_, a2_, acc[9]);          \
    acc[10] = MF(w2_, a2_, acc[10]); acc[11] = MF(w3_, a2_, acc[11]);         \
    acc[12] = MF(w0_, a3_, acc[12]); acc[13] = MF(w1_, a3_, acc[13]);         \
    acc[14] = MF(w2_, a3_, acc[14]); acc[15] = MF(w3_, a3_, acc[15]);         \
  } while (0)

// one group: issue next-group DMA, 2 barrier-free ksteps, 1 barrier
// (barrier drains this wave's vmcnt => staged group ready; buf reads done).
#define LGROUP(G, HASN, NGOFF) do {                                           \
    if (HASN) STAGEG((NGOFF), (((G)+1)&1));                                   \
    KSTEPC(2*(G)); KSTEPC(2*(G)+1);                                           \
    __syncthreads();                                                          \
  } while (0)

// full layer: entering, wbuf0 holds this layer's group 0 (chunks 0,1).
// Group 3 stages the NEXT layer's group 0 into wbuf0 (parity (3+1)&1 = 0).
#define LAYERC3(LOFF, NLOFF, LAST) do {                                       \
    _Pragma("unroll")                                                         \
    for (int i_ = 0; i_ < 16; ++i_) acc[i_] = (f32x4){0.f, 0.f, 0.f, 0.f};    \
    LGROUP(0, 1, (LOFF) + 32768);                                             \
    LGROUP(1, 1, (LOFF) + 65536);                                             \
    LGROUP(2, 1, (LOFF) + 98304);                                             \
    LGROUP(3, !(LAST), (NLOFF));                                              \
  } while (0)

// bias+relu -> bf16 writeback into swizzled act via cvt_pk (no barrier)
#define LAYER_WB3(BIAS) do {                                                  \
    _Pragma("unroll")                                                         \
    for (int nt_ = 0; nt_ < 4; ++nt_) {                                       \
      f32x4 bv_ = *(const f32x4*)&(BIAS)[nW + nt_*16 + lk*4];                 \
      const int cb_ = (cwb + nt_*32) ^ xwb;                                   \
      _Pragma("unroll")                                                       \
      for (int mt_ = 0; mt_ < 4; ++mt_) {                                     \
        f32x4 a_ = acc[mt_*4 + nt_];                                          \
        unsigned int lo_ = pk2bf(fmaxf(a_[0] + bv_[0], 0.f),                  \
                                 fmaxf(a_[1] + bv_[1], 0.f));                 \
        unsigned int hi_ = pk2bf(fmaxf(a_[2] + bv_[2], 0.f),                  \
                                 fmaxf(a_[3] + bv_[3], 0.f));                 \
        *(uint2*)(lds + ((m0 + mt_*16 + lr) << 9) + cb_) = make_uint2(lo_, hi_); \
      }                                                                       \
    }                                                                         \
  } while (0)

__global__ __launch_bounds__(768, 3)
__attribute__((amdgpu_waves_per_eu(3, 3)))
void liif_main(
    const float* __restrict__ coord, const float* __restrict__ cell,
    const float* __restrict__ P,  const float* __restrict__ W0,
    const unsigned char* __restrict__ img,
    const float* __restrict__ b1, const float* __restrict__ b2,
    const float* __restrict__ b3, const float* __restrict__ b4,
    const float* __restrict__ w4t, float* __restrict__ out)
{
  __shared__ __align__(16) unsigned char lds[163840];
  int*   lin_s = (int*)  (lds + WBASE);         // overlay in wbuf0 (pre-GEMM)
  f32x4* rel4  = (f32x4*)(lds + WBASE + 1024);
  float* predp = (float*)lds;                   // [4 wc][192 m][3 o] = 9.2 KB

  const int t   = threadIdx.x;
  const int blk = blockIdx.x;
  const int b   = (blk >= NB) ? 1 : 0;
  const int q0  = (blk - b*NB) * TQ;

  const int lane = t & 63;
  const int w    = t >> 6;              // 0..11
  const int m0   = (w >> 2) * 64;       // wave row base (0/64/128)
  const int wc   = w & 3;
  const int nW   = wc * 64;             // wave col base
  const int lr   = lane & 15;
  const int lk   = lane >> 4;

  // DMA staging offsets (per-lane global; wave-uniform LDS base)
  const size_t sgoff = (size_t)t * 16;
  const int    swoff = w * 1024;

  // W-read base: lane-ordered image => conflict-free (+ nt*1024 per frag)
  const int lwoff = wc*4096 + lane*16;
  // act-read bases (swizzle: colbyte ^ ((row&7)<<4), split into xl | xb6)
  const int xl  = (lr & 3) << 4;
  const int xb6 = ((lr >> 2) & 1) << 6;
  const int rb0 = ((m0 +  0 + lr) << 9) + ((lk << 4) ^ xl);
  const int rb1 = ((m0 + 16 + lr) << 9) + ((lk << 4) ^ xl);
  const int rb2 = ((m0 + 32 + lr) << 9) + ((lk << 4) ^ xl);
  const int rb3 = ((m0 + 48 + lr) << 9) + ((lk << 4) ^ xl);
  // writeback constants
  const int cwb = wc*128 + lk*8;
  const int xwb = (lr & 7) << 4;

  // ---- Phase A: indices + packed rel coords into wbuf0-overlay misc -------
  if (t < NEV) {
    const int e = t;
    int q = q0 + (e >> 2);
    if (q > 65535) q = 65535;           // ragged tail: clamp (output guarded)
    const int s = e & 3;                // [(-1,-1),(-1,1),(1,-1),(1,1)]
    const size_t cbase = (((size_t)b << 16) + q) * 2;
    float c0 = coord[cbase + 0];
    float c1 = coord[cbase + 1];
    float r0, r1; int ir, ic;
    rel_calc(c0, c1, s, r0, r1, ir, ic);
    lin_s[e] = ir*HH + ic;
    rel4[e] = (f32x4){r0, r1,
                      __fmul_rn(cell[cbase + 0], 48.0f),
                      __fmul_rn(cell[cbase + 1], 48.0f)};
  }
  __syncthreads();

  // ---- Phase B: h0 -> swizzled act. Wave = 16 rows; thread = 4 cols -------
  {
    const int cg = lane;                // col quad: cols cg*4..+3
    const float* w0t = W0 + (size_t)512*HID + cg*4;
    f32x4 wr0 = *(const f32x4*)(w0t);
    f32x4 wr1 = *(const f32x4*)(w0t + 256);
    f32x4 wr2 = *(const f32x4*)(w0t + 512);
    f32x4 wr3 = *(const f32x4*)(w0t + 768);
    const float* Pb = P + (size_t)b * NPOS * HID + cg*4;
    const int wb = cg * 8;              // byte col of this quad
    #pragma unroll 2
    for (int i = 0; i < 16; ++i) {
      const int e = w*16 + i;
      const int lin = lin_s[e];         // dword broadcast
      f32x4 rel = rel4[e];              // b128 broadcast
      f32x4 pv = *(const f32x4*)(Pb + (size_t)lin*HID);   // coalesced 1KB/row
      float v0 = pv[0] + rel[0]*wr0[0] + rel[1]*wr1[0] + rel[2]*wr2[0] + rel[3]*wr3[0];
      float v1 = pv[1] + rel[0]*wr0[1] + rel[1]*wr1[1] + rel[2]*wr2[1] + rel[3]*wr3[1];
      float v2 = pv[2] + rel[0]*wr0[2] + rel[1]*wr1[2] + rel[2]*wr2[2] + rel[3]*wr3[2];
      float v3 = pv[3] + rel[0]*wr0[3] + rel[1]*wr1[3] + rel[2]*wr2[3] + rel[3]*wr3[3];
      unsigned int lo = pk2bf(fmaxf(v0, 0.f), fmaxf(v1, 0.f));
      unsigned int hi = pk2bf(fmaxf(v2, 0.f), fmaxf(v3, 0.f));
      *(uint2*)(lds + (e << 9) + (wb ^ ((e & 7) << 4))) = make_uint2(lo, hi);
    }
  }
  __syncthreads();                      // act ready; misc reads done

  // prologue: stage L1 group0 (chunks 0,1) into wbuf0, drain
  STAGEG(0, 0);
  __syncthreads();

  f32x4 acc[16];
  // ---- Layer 1 -------------------------------------------------------------
  LAYERC3(0, 131072, 0);                // group3 stages L2.G0 -> wbuf0
  LAYER_WB3(b1);
  __syncthreads();                      // act visible

  // ---- Layer 2 -------------------------------------------------------------
  LAYERC3(131072, 262144, 0);           // group3 stages L3.G0 -> wbuf0
  LAYER_WB3(b2);
  __syncthreads();

  // ---- Layer 3 -------------------------------------------------------------
  LAYERC3(262144, 0, 1);
  // last group barrier done: all act reads complete (predp overlay safe)

  // ---- fused final layer, per-o passes (register-only on acc) -------------
  {
    #pragma unroll
    for (int o = 0; o < 3; ++o) {
      float p4[4] = {0.f, 0.f, 0.f, 0.f};
      #pragma unroll
      for (int nt = 0; nt < 4; ++nt) {
        f32x4 bv = *(const f32x4*)&b3[nW + nt*16 + lk*4];
        f32x4 wv = *(const f32x4*)&w4t[o*256 + nW + nt*16 + lk*4];
        #pragma unroll
        for (int mt = 0; mt < 4; ++mt) {
          f32x4 a = acc[mt*4 + nt];
          #pragma unroll
          for (int j = 0; j < 4; ++j)
            p4[mt] += fmaxf(a[j] + bv[j], 0.f) * wv[j];
        }
      }
      #pragma unroll
      for (int mt = 0; mt < 4; ++mt) {
        float s = p4[mt];
        s += __shfl_xor(s, 16);
        s += __shfl_xor(s, 32);
        p4[mt] = s;
      }
      if (lk == 0) {
        #pragma unroll
        for (int mt = 0; mt < 4; ++mt)
          predp[wc*576 + (m0 + mt*16 + lr)*3 + o] = p4[mt];
      }
    }
  }
  __syncthreads();

  // ---- blend: pred[e][o] = b4 + sum_wc partials; w[s] = area[3-s]/tot -----
  if (t < TQ*3) {
    const int q = t / 3, o = t - (t/3)*3;
    const int qq = q0 + q;
    if (qq < 65536) {
      const int eb = q*4;
      const size_t cbase = (((size_t)b << 16) + qq) * 2;
      float c0 = coord[cbase + 0];
      float c1 = coord[cbase + 1];
      float ar[4];
      #pragma unroll
      for (int s = 0; s < 4; ++s) {
        float r0, r1; int ir, ic;
        rel_calc(c0, c1, s, r0, r1, ir, ic);
        ar[s] = __fadd_rn(fabsf(__fmul_rn(r0, r1)), 1e-9f);
      }
      float pe[4];
      #pragma unroll
      for (int s = 0; s < 4; ++s) {
        const int e = eb + s;
        pe[s] = b4[o] + predp[e*3 + o] + predp[576 + e*3 + o]
                      + predp[1152 + e*3 + o] + predp[1728 + e*3 + o];
      }
      float tot = ((ar[0] + ar[1]) + ar[2]) + ar[3];
      float rv = (pe[0]*ar[3] + pe[1]*ar[2] + pe[2]*ar[1] + pe[3]*ar[0]) / tot;
      out[(((size_t)b << 16) + qq)*3 + o] = rv;
    }
  }
}

// ---------------------------------------------------------------------------
extern "C" void kernel_launch(void* const* d_in, const int* in_sizes, int n_in,
                              void* d_out, int out_size, void* d_ws, size_t ws_size,
                              hipStream_t stream)
{
  const float* feat  = (const float*)d_in[0];
  const float* coord = (const float*)d_in[1];
  const float* cell  = (const float*)d_in[2];
  const float* W0    = (const float*)d_in[3];
  const float* b0    = (const float*)d_in[4];
  const float* W1    = (const float*)d_in[5];
  const float* b1    = (const float*)d_in[6];
  const float* W2    = (const float*)d_in[7];
  const float* b2    = (const float*)d_in[8];
  const float* W3    = (const float*)d_in[9];
  const float* b3    = (const float*)d_in[10];
  const float* W4    = (const float*)d_in[11];
  const float* b4    = (const float*)d_in[12];
  float* outp = (float*)d_out;

  // ws layout: P f32 [2*2304*256] = 4,718,592 B | W image 3*131072 = 393,216 B
  //            | W4t f32 3*256 = 3,072 B
  float*         P    = (float*)d_ws;
  unsigned char* imgp = (unsigned char*)d_ws + 4718592;
  float*         w4tp = (float*)((unsigned char*)d_ws + 4718592 + 393216);

  hipLaunchKernelGGL(liif_precompute, dim3(2*(NPOS/4)), dim3(256), 0, stream,
                     feat, W0, b0, P);
  hipLaunchKernelGGL(liif_convert, dim3(25), dim3(256), 0, stream,
                     W1, W2, W3, W4, imgp, w4tp);
  hipLaunchKernelGGL(liif_main, dim3(2*NB), dim3(768), 0, stream,
                     coord, cell, P, W0, imgp, b1, b2, b3, b4, w4tp, outp);
}

// Round 16
// 280.564 us; speedup vs baseline: 1.0396x; 1.0396x over previous
//
#include <hip/hip_runtime.h>
#include <hip/hip_bf16.h>
#include <math.h>

#define HH    48
#define CFEAT 512
#define HID   256
#define NPOS  (HH*HH)   // 2304
#define TQ    48        // queries per block
#define NEV   192       // evals per block = TQ*4
#define NB    1366      // blocks per batch = ceil(65536/48)

typedef __attribute__((ext_vector_type(8))) short bf16x8;
typedef __attribute__((ext_vector_type(4))) float f32x4;

static __device__ __forceinline__ unsigned short f2bf(float x) {
  unsigned int u = __float_as_uint(x);
  u += 0x7fffu + ((u >> 16) & 1u);     // RNE
  return (unsigned short)(u >> 16);
}

// packed f32x2 -> bf16x2 via v_cvt_pk_bf16_f32 (RNE)
static __device__ __forceinline__ unsigned int pk2bf(float a, float b) {
  __hip_bfloat162 h2 = __float22bfloat162_rn(make_float2(a, b));
  unsigned int u; __builtin_memcpy(&u, &h2, 4); return u;
}

// index/rel math shared (bit-exact) by Phase A and blend-area recompute
static __device__ __forceinline__ void rel_calc(float c0, float c1, int s,
                                                float& r0, float& r1,
                                                int& ir, int& ic) {
  float vx = (s & 2) ? 1.0f : -1.0f;
  float vy = (s & 1) ? 1.0f : -1.0f;
  const float RXY = (float)(1.0/48.0);
  const float CLO = (float)(-1.0 + 1e-6);
  const float CHI = (float)( 1.0 - 1e-6);
  float gx = __fadd_rn(c0, __fadd_rn(__fmul_rn(vx, RXY), 1e-6f));
  float gy = __fadd_rn(c1, __fadd_rn(__fmul_rn(vy, RXY), 1e-6f));
  gx = fminf(fmaxf(gx, CLO), CHI);
  gy = fminf(fmaxf(gy, CLO), CHI);
  float xr = __fmul_rn(__fsub_rn(__fmul_rn(__fadd_rn(gx, 1.0f), 48.0f), 1.0f), 0.5f);
  float xc = __fmul_rn(__fsub_rn(__fmul_rn(__fadd_rn(gy, 1.0f), 48.0f), 1.0f), 0.5f);
  ir = (int)rintf(xr); ir = ir < 0 ? 0 : (ir > HH-1 ? HH-1 : ir);
  ic = (int)rintf(xc); ic = ic < 0 ? 0 : (ic > HH-1 ? HH-1 : ic);
  const float T2 = (float)(2.0/48.0);
  float qcr = __fsub_rn(__fmul_rn(__fadd_rn((float)ir, 0.5f), T2), 1.0f);
  float qcc = __fsub_rn(__fmul_rn(__fadd_rn((float)ic, 0.5f), T2), 1.0f);
  r0 = __fmul_rn(__fsub_rn(c0, qcr), 48.0f);
  r1 = __fmul_rn(__fsub_rn(c1, qcc), 48.0f);
}

// ---------------------------------------------------------------------------
// Kernel 1: P[b][pos][n] = b0[n] + sum_c feat[b][c][pos] * W0[c][n]  (fp32)
// ---------------------------------------------------------------------------
__global__ __launch_bounds__(256) void liif_precompute(
    const float* __restrict__ feat, const float* __restrict__ W0,
    const float* __restrict__ b0, float* __restrict__ P)
{
  int blk = blockIdx.x;                 // 0..1151
  int b   = blk / (NPOS/4);
  int p0  = (blk - b*(NPOS/4)) * 4;
  int n   = threadIdx.x;
  const float* f = feat + (size_t)b * CFEAT * NPOS + p0;
  float bias = b0[n];
  float a0 = bias, a1 = bias, a2 = bias, a3 = bias;
  #pragma unroll 4
  for (int c = 0; c < CFEAT; ++c) {
    float w = W0[c*HID + n];
    const float* fr = f + (size_t)c * NPOS;
    a0 += fr[0]*w; a1 += fr[1]*w; a2 += fr[2]*w; a3 += fr[3]*w;
  }
  float* Pp = P + ((size_t)b*NPOS + p0)*HID + n;
  Pp[0*HID] = a0; Pp[1*HID] = a1; Pp[2*HID] = a2; Pp[3*HID] = a3;
}

// ---------------------------------------------------------------------------
// Kernel 2: build pre-permuted W image for linear global_load_lds staging.
// Chunk (l,kc) = 16 KB; 16-B unit p (0..1023):
//   wc = p>>8, nt = (p>>6)&3, lane = p&63, lr = lane&15, lk = lane>>4
//   n = wc*64 + nt*16 + lr ; unit holds Wt[n][kc*32 + lk*8 .. +8]
// Layer stride = 131072 B.  Plus W4 image (8 KB): unit p (0..511):
//   kc = p>>6, lane = p&63, n = lane&15, k0 = kc*32 + (lane>>4)*8;
//   holds W4t[n][k0..+8] (W4t[o][k] = W4[k][o] for o<3, else 0).
// ---------------------------------------------------------------------------
__global__ __launch_bounds__(256) void liif_convert(
    const float* __restrict__ W1, const float* __restrict__ W2,
    const float* __restrict__ W3, const float* __restrict__ W4,
    unsigned char* __restrict__ img, unsigned char* __restrict__ w4i)
{
  int blk = blockIdx.x, t = threadIdx.x;
  if (blk < 24) {
    int l = blk >> 3, kc = blk & 7;
    const float* W = (l == 0) ? W1 : (l == 1) ? W2 : W3;
    unsigned short* dst = (unsigned short*)(img + (size_t)blk * 16384);
    #pragma unroll 1
    for (int s = 0; s < 4; ++s) {
      int p    = t + s*256;
      int wc   = p >> 8;
      int nt   = (p >> 6) & 3;
      int lane = p & 63;
      int lr   = lane & 15, lk = lane >> 4;
      int n    = wc*64 + nt*16 + lr;
      int k0   = kc*32 + lk*8;
      #pragma unroll
      for (int j = 0; j < 8; ++j)
        dst[p*8 + j] = f2bf(W[(k0 + j)*256 + n]);
    }
  } else {
    unsigned short* dst = (unsigned short*)w4i;
    #pragma unroll
    for (int u = 0; u < 2; ++u) {
      int p    = t + u*256;             // 0..511
      int kc   = p >> 6;
      int lane = p & 63;
      int n    = lane & 15;
      int k0   = kc*32 + (lane >> 4)*8;
      #pragma unroll
      for (int j = 0; j < 8; ++j)
        dst[p*8 + j] = (n < 3) ? f2bf(W4[(k0 + j)*3 + n]) : (unsigned short)0;
    }
  }
}

// ---------------------------------------------------------------------------
// Kernel 3: fused main. 192 evals/block, 768 thr / 12 waves (3x4 of 64x64).
// act: XOR-swizzled [192 rows][512 B] = 96 KB.
// W: 32 KB groups (2 K-chunks) double-buffered via global_load_lds;
// per group: issue next DMA, 2 barrier-free ksteps, 1 barrier.
// Final 256->3 layer as MFMA (W4 padded to 16 outputs; 8 MFMA/wave,
// no shfl reduce, no cross-wave sums). LDS = exactly 160 KiB.
// ---------------------------------------------------------------------------
// LDS map:
//   [0, 98304)        act (swizzled). After final: predp overlay (2.3 KB).
//   [98304, 131072)   wbuf0 (32 KB); first 4 KB = {lin_s, rel4} in Phase A/B;
//                     first 8 KB = W4 frag image during final layer.
//   [131072, 163840)  wbuf1 (32 KB).

#define WBASE  98304

#define MF(A, B, C) __builtin_amdgcn_mfma_f32_16x16x32_bf16((A), (B), (C), 0, 0, 0)

#define AS1(p) ((const __attribute__((address_space(1))) void*)(unsigned long long)(const void*)(p))
#define AS3(p) ((__attribute__((address_space(3))) void*)(unsigned int)(unsigned long long)(void*)(p))

// DMA one 32 KB group (32 x 1KB slices) with 12 waves:
// ops j=0,1 all waves (slices j*12+w), op j=2 waves 0..7 (slices 24..31).
#define STAGEG(GOFF, BUF) do {                                                \
    __builtin_amdgcn_global_load_lds(                                         \
        AS1(img + (GOFF) + sgoff),                                            \
        AS3(lds + WBASE + (BUF)*32768 + swoff), 16, 0, 0);                    \
    __builtin_amdgcn_global_load_lds(                                         \
        AS1(img + (GOFF) + 12288 + sgoff),                                    \
        AS3(lds + WBASE + (BUF)*32768 + 12288 + swoff), 16, 0, 0);            \
    if (w < 8)                                                                \
      __builtin_amdgcn_global_load_lds(                                       \
          AS1(img + (GOFF) + 24576 + sgoff),                                  \
          AS3(lds + WBASE + (BUF)*32768 + 24576 + swoff), 16, 0, 0);          \
  } while (0)

// one K=32 step: 4 W + 4 act b128 reads, 16 MFMA. NO barrier.
// W chunk KC lives at wbuf[(KC>>1)&1] + (KC&1)*16384.
#define KSTEPC(KC) do {                                                       \
    const unsigned char* wb_ = lds + WBASE + (((KC) >> 1) & 1)*32768          \
                             + (((KC) & 1)*16384) + lwoff;                    \
    bf16x8 w0_ = *(const bf16x8*)(wb_ + 0);                                   \
    bf16x8 w1_ = *(const bf16x8*)(wb_ + 1024);                                \
    bf16x8 w2_ = *(const bf16x8*)(wb_ + 2048);                                \
    bf16x8 w3_ = *(const bf16x8*)(wb_ + 3072);                                \
    const int ko_ = (((KC) << 6) ^ xb6);                                      \
    bf16x8 a0_ = *(const bf16x8*)(lds + rb0 + ko_);                           \
    bf16x8 a1_ = *(const bf16x8*)(lds + rb1 + ko_);                           \
    bf16x8 a2_ = *(const bf16x8*)(lds + rb2 + ko_);                           \
    bf16x8 a3_ = *(const bf16x8*)(lds + rb3 + ko_);                           \
    acc[0]  = MF(w0_, a0_, acc[0]);  acc[1]  = MF(w1_, a0_, acc[1]);          \
    acc[2]  = MF(w2_, a0_, acc[2]);  acc[3]  = MF(w3_, a0_, acc[3]);          \
    acc[4]  = MF(w0_, a1_, acc[4]);  acc[5]  = MF(w1_, a1_, acc[5]);          \
    acc[6]  = MF(w2_, a1_, acc[6]);  acc[7]  = MF(w3_, a1_, acc[7]);          \
    acc[8]  = MF(w0_, a2_, acc[8]);  acc[9]  = MF(w1_, a2_, acc[9]);          \
    acc[10] = MF(w2_, a2_, acc[10]); acc[11] = MF(w3_, a2_, acc[11]);         \
    acc[12] = MF(w0_, a3_, acc[12]); acc[13] = MF(w1_, a3_, acc[13]);         \
    acc[14] = MF(w2_, a3_, acc[14]); acc[15] = MF(w3_, a3_, acc[15]);         \
  } while (0)

// one group: issue next-group DMA, 2 barrier-free ksteps, 1 barrier
#define LGROUP(G, HASN, NGOFF) do {                                           \
    if (HASN) STAGEG((NGOFF), (((G)+1)&1));                                   \
    KSTEPC(2*(G)); KSTEPC(2*(G)+1);                                           \
    __syncthreads();                                                          \
  } while (0)

// L1/L2: entering, wbuf0 holds this layer's group 0 (chunks 0,1);
// group 3 stages the NEXT layer's group 0 into wbuf0.
#define LAYERC3(LOFF, NLOFF) do {                                             \
    _Pragma("unroll")                                                         \
    for (int i_ = 0; i_ < 16; ++i_) acc[i_] = (f32x4){0.f, 0.f, 0.f, 0.f};    \
    LGROUP(0, 1, (LOFF) + 32768);                                             \
    LGROUP(1, 1, (LOFF) + 65536);                                             \
    LGROUP(2, 1, (LOFF) + 98304);                                             \
    LGROUP(3, 1, (NLOFF));                                                    \
  } while (0)

// bias+relu -> bf16 writeback into swizzled act via cvt_pk (no barrier)
#define LAYER_WB3(BIAS) do {                                                  \
    _Pragma("unroll")                                                         \
    for (int nt_ = 0; nt_ < 4; ++nt_) {                                       \
      f32x4 bv_ = *(const f32x4*)&(BIAS)[nW + nt_*16 + lk*4];                 \
      const int cb_ = (cwb + nt_*32) ^ xwb;                                   \
      _Pragma("unroll")                                                       \
      for (int mt_ = 0; mt_ < 4; ++mt_) {                                     \
        f32x4 a_ = acc[mt_*4 + nt_];                                          \
        unsigned int lo_ = pk2bf(fmaxf(a_[0] + bv_[0], 0.f),                  \
                                 fmaxf(a_[1] + bv_[1], 0.f));                 \
        unsigned int hi_ = pk2bf(fmaxf(a_[2] + bv_[2], 0.f),                  \
                                 fmaxf(a_[3] + bv_[3], 0.f));                 \
        *(uint2*)(lds + ((m0 + mt_*16 + lr) << 9) + cb_) = make_uint2(lo_, hi_); \
      }                                                                       \
    }                                                                         \
  } while (0)

__global__ __launch_bounds__(768, 3)
__attribute__((amdgpu_waves_per_eu(3, 3)))
void liif_main(
    const float* __restrict__ coord, const float* __restrict__ cell,
    const float* __restrict__ P,  const float* __restrict__ W0,
    const unsigned char* __restrict__ img,
    const unsigned char* __restrict__ w4i,
    const float* __restrict__ b1, const float* __restrict__ b2,
    const float* __restrict__ b3, const float* __restrict__ b4,
    float* __restrict__ out)
{
  __shared__ __align__(16) unsigned char lds[163840];
  int*   lin_s = (int*)  (lds + WBASE);         // overlay in wbuf0 (pre-GEMM)
  f32x4* rel4  = (f32x4*)(lds + WBASE + 1024);
  float* predp = (float*)lds;                   // [192 m][3 o] = 2.3 KB

  const int t   = threadIdx.x;
  const int blk = blockIdx.x;
  const int b   = (blk >= NB) ? 1 : 0;
  const int q0  = (blk - b*NB) * TQ;

  const int lane = t & 63;
  const int w    = t >> 6;              // 0..11
  const int m0   = (w >> 2) * 64;       // wave row base (0/64/128)
  const int wc   = w & 3;
  const int nW   = wc * 64;             // wave col base
  const int lr   = lane & 15;
  const int lk   = lane >> 4;

  // DMA staging offsets (per-lane global; wave-uniform LDS base)
  const size_t sgoff = (size_t)t * 16;
  const int    swoff = w * 1024;

  // W-read base: lane-ordered image => conflict-free (+ nt*1024 per frag)
  const int lwoff = wc*4096 + lane*16;
  // act-read bases (swizzle: colbyte ^ ((row&7)<<4), split into xl | xb6)
  const int xl  = (lr & 3) << 4;
  const int xb6 = ((lr >> 2) & 1) << 6;
  const int rb0 = ((m0 +  0 + lr) << 9) + ((lk << 4) ^ xl);
  const int rb1 = ((m0 + 16 + lr) << 9) + ((lk << 4) ^ xl);
  const int rb2 = ((m0 + 32 + lr) << 9) + ((lk << 4) ^ xl);
  const int rb3 = ((m0 + 48 + lr) << 9) + ((lk << 4) ^ xl);
  // writeback constants
  const int cwb = wc*128 + lk*8;
  const int xwb = (lr & 7) << 4;

  // ---- Phase A: indices + packed rel coords into wbuf0-overlay misc -------
  if (t < NEV) {
    const int e = t;
    int q = q0 + (e >> 2);
    if (q > 65535) q = 65535;           // ragged tail: clamp (output guarded)
    const int s = e & 3;                // [(-1,-1),(-1,1),(1,-1),(1,1)]
    const size_t cbase = (((size_t)b << 16) + q) * 2;
    float c0 = coord[cbase + 0];
    float c1 = coord[cbase + 1];
    float r0, r1; int ir, ic;
    rel_calc(c0, c1, s, r0, r1, ir, ic);
    lin_s[e] = ir*HH + ic;
    rel4[e] = (f32x4){r0, r1,
                      __fmul_rn(cell[cbase + 0], 48.0f),
                      __fmul_rn(cell[cbase + 1], 48.0f)};
  }
  __syncthreads();

  // ---- Phase B: h0 -> swizzled act. Wave = 16 rows; thread = 4 cols -------
  {
    const int cg = lane;                // col quad: cols cg*4..+3
    const float* w0t = W0 + (size_t)512*HID + cg*4;
    f32x4 wr0 = *(const f32x4*)(w0t);
    f32x4 wr1 = *(const f32x4*)(w0t + 256);
    f32x4 wr2 = *(const f32x4*)(w0t + 512);
    f32x4 wr3 = *(const f32x4*)(w0t + 768);
    const float* Pb = P + (size_t)b * NPOS * HID + cg*4;
    const int wb = cg * 8;              // byte col of this quad
    #pragma unroll 2
    for (int i = 0; i < 16; ++i) {
      const int e = w*16 + i;
      const int lin = lin_s[e];         // dword broadcast
      f32x4 rel = rel4[e];              // b128 broadcast
      f32x4 pv = *(const f32x4*)(Pb + (size_t)lin*HID);   // coalesced 1KB/row
      float v0 = pv[0] + rel[0]*wr0[0] + rel[1]*wr1[0] + rel[2]*wr2[0] + rel[3]*wr3[0];
      float v1 = pv[1] + rel[0]*wr0[1] + rel[1]*wr1[1] + rel[2]*wr2[1] + rel[3]*wr3[1];
      float v2 = pv[2] + rel[0]*wr0[2] + rel[1]*wr1[2] + rel[2]*wr2[2] + rel[3]*wr3[2];
      float v3 = pv[3] + rel[0]*wr0[3] + rel[1]*wr1[3] + rel[2]*wr2[3] + rel[3]*wr3[3];
      unsigned int lo = pk2bf(fmaxf(v0, 0.f), fmaxf(v1, 0.f));
      unsigned int hi = pk2bf(fmaxf(v2, 0.f), fmaxf(v3, 0.f));
      *(uint2*)(lds + (e << 9) + (wb ^ ((e & 7) << 4))) = make_uint2(lo, hi);
    }
  }
  __syncthreads();                      // act ready; misc reads done

  // prologue: stage L1 group0 (chunks 0,1) into wbuf0, drain
  STAGEG(0, 0);
  __syncthreads();

  f32x4 acc[16];
  // ---- Layer 1 -------------------------------------------------------------
  LAYERC3(0, 131072);                   // group3 stages L2.G0 -> wbuf0
  LAYER_WB3(b1);
  __syncthreads();                      // act visible

  // ---- Layer 2 -------------------------------------------------------------
  LAYERC3(131072, 262144);              // group3 stages L3.G0 -> wbuf0
  LAYER_WB3(b2);
  __syncthreads();

  // ---- Layer 3 (group 3 stages the 8 KB W4 frag image into wbuf0) ---------
  {
    #pragma unroll
    for (int i_ = 0; i_ < 16; ++i_) acc[i_] = (f32x4){0.f, 0.f, 0.f, 0.f};
    LGROUP(0, 1, 262144 + 32768);
    LGROUP(1, 1, 262144 + 65536);
    LGROUP(2, 1, 262144 + 98304);
    if (w < 8)
      __builtin_amdgcn_global_load_lds(AS1(w4i + sgoff),
                                       AS3(lds + WBASE + swoff), 16, 0, 0);
    KSTEPC(6); KSTEPC(7);
    __syncthreads();                    // W4 image staged; wbuf reads done
  }
  LAYER_WB3(b3);                        // h3 -> act (bf16, relu)
  __syncthreads();                      // act visible to all waves

  // ---- final 256->16(3) layer via MFMA: wave w owns rows w*16..+15 --------
  {
    f32x4 acc4 = (f32x4){0.f, 0.f, 0.f, 0.f};
    const int fr_ = ((w << 4) + lr) << 9;
    #pragma unroll
    for (int kc = 0; kc < 8; ++kc) {
      bf16x8 wf = *(const bf16x8*)(lds + WBASE + kc*1024 + lane*16);
      bf16x8 af = *(const bf16x8*)(lds + fr_ + ((kc << 6) ^ xb6) + ((lk << 4) ^ xl));
      acc4 = MF(wf, af, acc4);
    }
    __syncthreads();                    // all act reads done (predp overlay)
    if (lk == 0) {                      // lane holds pred[m=w*16+lr][o=j]
      float* pp = predp + ((w << 4) + lr)*3;
      pp[0] = acc4[0] + b4[0];
      pp[1] = acc4[1] + b4[1];
      pp[2] = acc4[2] + b4[2];
    }
  }
  __syncthreads();

  // ---- blend: w[s] = area[3-s]/tot -----------------------------------------
  if (t < TQ*3) {
    const int q = t / 3, o = t - (t/3)*3;
    const int qq = q0 + q;
    if (qq < 65536) {
      const int eb = q*4;
      const size_t cbase = (((size_t)b << 16) + qq) * 2;
      float c0 = coord[cbase + 0];
      float c1 = coord[cbase + 1];
      float ar[4];
      #pragma unroll
      for (int s = 0; s < 4; ++s) {
        float r0, r1; int ir, ic;
        rel_calc(c0, c1, s, r0, r1, ir, ic);
        ar[s] = __fadd_rn(fabsf(__fmul_rn(r0, r1)), 1e-9f);
      }
      float p0 = predp[(eb+0)*3 + o];
      float p1 = predp[(eb+1)*3 + o];
      float p2 = predp[(eb+2)*3 + o];
      float p3 = predp[(eb+3)*3 + o];
      float tot = ((ar[0] + ar[1]) + ar[2]) + ar[3];
      float rv = (p0*ar[3] + p1*ar[2] + p2*ar[1] + p3*ar[0]) / tot;
      out[(((size_t)b << 16) + qq)*3 + o] = rv;
    }
  }
}

// ---------------------------------------------------------------------------
extern "C" void kernel_launch(void* const* d_in, const int* in_sizes, int n_in,
                              void* d_out, int out_size, void* d_ws, size_t ws_size,
                              hipStream_t stream)
{
  const float* feat  = (const float*)d_in[0];
  const float* coord = (const float*)d_in[1];
  const float* cell  = (const float*)d_in[2];
  const float* W0    = (const float*)d_in[3];
  const float* b0    = (const float*)d_in[4];
  const float* W1    = (const float*)d_in[5];
  const float* b1    = (const float*)d_in[6];
  const float* W2    = (const float*)d_in[7];
  const float* b2    = (const float*)d_in[8];
  const float* W3    = (const float*)d_in[9];
  const float* b3    = (const float*)d_in[10];
  const float* W4    = (const float*)d_in[11];
  const float* b4    = (const float*)d_in[12];
  float* outp = (float*)d_out;

  // ws layout: P f32 [2*2304*256] = 4,718,592 B | W image 3*131072 = 393,216 B
  //            | W4 frag image 8,192 B
  float*         P    = (float*)d_ws;
  unsigned char* imgp = (unsigned char*)d_ws + 4718592;
  unsigned char* w4ip = (unsigned char*)d_ws + 4718592 + 393216;

  hipLaunchKernelGGL(liif_precompute, dim3(2*(NPOS/4)), dim3(256), 0, stream,
                     feat, W0, b0, P);
  hipLaunchKernelGGL(liif_convert, dim3(25), dim3(256), 0, stream,
                     W1, W2, W3, W4, imgp, w4ip);
  hipLaunchKernelGGL(liif_main, dim3(2*NB), dim3(768), 0, stream,
                     coord, cell, P, W0, imgp, w4ip, b1, b2, b3, b4, outp);
}